// Round 2
// baseline (695.886 us; speedup 1.0000x reference)
//
#include <hip/hip_runtime.h>
#include <stdint.h>

typedef uint16_t u16;
typedef uint32_t u32;
typedef __attribute__((ext_vector_type(4))) int   int4v;    // 16B
typedef __attribute__((ext_vector_type(4))) short short4v;  // 8B
typedef __attribute__((ext_vector_type(8))) short short8;   // bf16x8 MFMA frag
typedef __attribute__((ext_vector_type(4))) float float4v;  // 16B / MFMA acc

// ---- helpers ----
__device__ __forceinline__ u16 f2bf(float f) {   // fp32 -> bf16 RNE
  u32 x = __float_as_uint(f);
  x += 0x7fffu + ((x >> 16) & 1u);
  return (u16)(x >> 16);
}

// B=128, T=2048, J=128, D=512  (fp32 inputs per reference)
#define BB 128
#define TT 2048
#define JJ 128
#define DD 512

// ---------------------------------------------------------------------------
// Kernel 1: U fp32 [B][J=128][D=512] -> Ut bf16 [B][D=512][J=128]
// ---------------------------------------------------------------------------
__global__ __launch_bounds__(256) void u_transpose(const float* __restrict__ U,
                                                   u16* __restrict__ Ut) {
  __shared__ u16 tile[128 * 72];
  const int t  = threadIdx.x;
  const int b  = blockIdx.x >> 3;
  const int d0 = (blockIdx.x & 7) << 6;
  const float* src = U + (size_t)b * (JJ * DD);
  u16* dst         = Ut + (size_t)b * (DD * JJ);
#pragma unroll
  for (int i = 0; i < 8; ++i) {            // 128 rows * 16 float4 = 2048 chunks
    int idx = i * 256 + t;
    int j = idx >> 4, c = idx & 15;        // c: float4 chunk in 64-wide slab
    float4v v = *(const float4v*)(src + (size_t)j * DD + d0 + c * 4);
    short4v p;
#pragma unroll
    for (int e = 0; e < 4; ++e) p[e] = (short)f2bf(v[e]);
    *(short4v*)(tile + j * 72 + c * 4) = p; // row stride 144B; 8B aligned
  }
  __syncthreads();
#pragma unroll
  for (int i = 0; i < 4; ++i) {            // 64 d-rows * 16 j-chunks = 1024
    int idx = i * 256 + t;
    int n = idx >> 4, cj = idx & 15;
    short8 vv;
#pragma unroll
    for (int k = 0; k < 8; ++k) vv[k] = (short)tile[(cj * 8 + k) * 72 + n];
    *(short8*)(dst + (size_t)(d0 + n) * JJ + cj * 8) = vv;
  }
}

// ---------------------------------------------------------------------------
// Kernel 2: fused softmax (fp32) + bf16 MFMA GEMM, fp32 out.
// Block = (b, tm): 128 t-rows x FULL 512 d-cols.
// Barrier-free main loop: Ut fragments are 16B-contiguous in the [D][J]
// layout, so bv loads come straight from L2 (Ut[b]=128KiB, XCD-resident via
// swizzle) -- no b_lds, no staging barriers, stores stream un-drained.
// LDS = a_lds only (32 KiB) -> 3 blocks/CU at launch_bounds(256,3).
// ---------------------------------------------------------------------------
__global__ __launch_bounds__(256, 3) void softmax_gemm(const float* __restrict__ S,
                                                       const u16* __restrict__ Ut,
                                                       float* __restrict__ O) {
  __shared__ __align__(16) u16 a_lds[128 * 128];   // 32 KiB (swizzled P tile)

  const int tid = threadIdx.x;
  // bijective XCD swizzle (2048 blocks % 8 == 0): same-b blocks share one L2
  const int bid = blockIdx.x;
  const int swz = (bid & 7) * 256 + (bid >> 3);
  const int b   = swz >> 4;
  const int tm  = swz & 15;
  const int wave = tid >> 6, lane = tid & 63;
  const int ml = lane & 15, quad = lane >> 4;
  const int wm = wave & 1, wn = wave >> 1;

  const u16* utb = Ut + (size_t)b * (DD * JJ);     // [512][128] bf16

  // ---- softmax: 2 threads per row, 64 fp32 each ----
  const int m = tid >> 1, h = tid & 1;
  const float* srow = S + ((size_t)b * TT + tm * 128 + m) * JJ + h * 64;
  float x[64];
#pragma unroll
  for (int c = 0; c < 16; ++c) {
    float4v v = ((const float4v*)srow)[c];
#pragma unroll
    for (int e = 0; e < 4; ++e) x[c * 4 + e] = v[e];
  }
  float mx = -1e30f;
#pragma unroll
  for (int e = 0; e < 64; ++e) mx = fmaxf(mx, x[e]);
  mx = fmaxf(mx, __shfl_xor(mx, 1, 64));
  float sum = 0.f;
#pragma unroll
  for (int e = 0; e < 64; ++e) { x[e] = __expf(x[e] - mx); sum += x[e]; }
  sum += __shfl_xor(sum, 1, 64);
  const float rs = 1.0f / sum;
  // write normalized bf16 into swizzled slab layout:
  // elem (m,k): s=k>>5, q=(k>>3)&3, phys chunk = q ^ ((m>>1)&3)
#pragma unroll
  for (int c = 0; c < 8; ++c) {
    short8 us;
#pragma unroll
    for (int e = 0; e < 8; ++e) us[e] = (short)f2bf(x[c * 8 + e] * rs);
    int s  = h * 2 + (c >> 2);
    int qp = (c & 3) ^ ((m >> 1) & 3);
    *(short8*)(a_lds + s * 4096 + m * 32 + qp * 8) = us;
  }

  __syncthreads();   // the ONLY barrier: a_lds now readable by all waves

  float* ob = O + ((size_t)b * TT + tm * 128) * DD;

  // per-lane invariant offsets
  const u16* bv_base = utb + (size_t)(wn * 64 + ml) * JJ + quad * 8;

#pragma unroll 1
  for (int tn = 0; tn < 4; ++tn) {
    float4v acc[4][4];
#pragma unroll
    for (int mi = 0; mi < 4; ++mi)
#pragma unroll
      for (int ni = 0; ni < 4; ++ni) {
        float4v z = {0.f, 0.f, 0.f, 0.f};
        acc[mi][ni] = z;
      }

    const u16* bv_tn = bv_base + (size_t)tn * 128 * JJ;

#pragma unroll
    for (int s = 0; s < 4; ++s) {
      // bv: Ut rows nn = tn*128 + wn*64 + ni*16 + ml, k = s*32 + quad*8 .. +7
      short8 bv[4];
#pragma unroll
      for (int ni = 0; ni < 4; ++ni)
        bv[ni] = *(const short8*)(bv_tn + (size_t)ni * 16 * JJ + s * 32);
      // av: P rows mm = wm*64 + mi*16 + ml, same k slab (swizzled chunks)
      short8 av[4];
#pragma unroll
      for (int mi = 0; mi < 4; ++mi) {
        int mm = wm * 64 + mi * 16 + ml;
        int qp = quad ^ ((mm >> 1) & 3);
        av[mi] = *(const short8*)(a_lds + s * 4096 + mm * 32 + qp * 8);
      }
#pragma unroll
      for (int mi = 0; mi < 4; ++mi)
#pragma unroll
        for (int ni = 0; ni < 4; ++ni)
          acc[mi][ni] = __builtin_amdgcn_mfma_f32_16x16x32_bf16(
              bv[ni], av[mi], acc[mi][ni], 0, 0, 0);
    }

    // ---- direct float4 stores from acc (no LDS epilogue, no drain) ----
    // acc[mi][ni][r]: t = tm*128 + wm*64 + mi*16 + ml,
    //                 d = tn*128 + wn*64 + ni*16 + quad*4 + r
#pragma unroll
    for (int mi = 0; mi < 4; ++mi) {
      const int t = wm * 64 + mi * 16 + ml;
#pragma unroll
      for (int ni = 0; ni < 4; ++ni) {
        const int d = tn * 128 + wn * 64 + ni * 16 + quad * 4;
        *(float4v*)(ob + (size_t)t * DD + d) = acc[mi][ni];
      }
    }
  }
}

// ---------------------------------------------------------------------------
extern "C" void kernel_launch(void* const* d_in, const int* in_sizes, int n_in,
                              void* d_out, int out_size, void* d_ws, size_t ws_size,
                              hipStream_t stream) {
  (void)in_sizes; (void)n_in; (void)out_size; (void)ws_size;
  const float* U = (const float*)d_in[0];  // [128][128][512] fp32
  const float* S = (const float*)d_in[1];  // [128][2048][128] fp32
  float* out = (float*)d_out;              // [128][2048][512] fp32
  u16* Ut    = (u16*)d_ws;                 // [128][512][128] bf16 = 8 MiB scratch

  u_transpose<<<BB * 8, 256, 0, stream>>>(U, Ut);
  softmax_gemm<<<BB * 16, 256, 0, stream>>>(S, Ut, out);
}

// Round 3
// 659.677 us; speedup vs baseline: 1.0549x; 1.0549x over previous
//
#include <hip/hip_runtime.h>
#include <stdint.h>

typedef uint16_t u16;
typedef uint32_t u32;
typedef __attribute__((ext_vector_type(4))) int   int4v;    // 16B
typedef __attribute__((ext_vector_type(4))) short short4v;  // 8B
typedef __attribute__((ext_vector_type(8))) short short8;   // bf16x8 MFMA frag
typedef __attribute__((ext_vector_type(4))) float float4v;  // 16B / MFMA acc

// ---- helpers ----
__device__ __forceinline__ u16 f2bf(float f) {   // fp32 -> bf16 RNE
  u32 x = __float_as_uint(f);
  x += 0x7fffu + ((x >> 16) & 1u);
  return (u16)(x >> 16);
}
__device__ __forceinline__ void llds16(const u16* g, u16* l) {
  // async global->LDS, 16B/lane; LDS dest = wave-uniform base + lane*16
  __builtin_amdgcn_global_load_lds(
      (const __attribute__((address_space(1))) void*)g,
      (__attribute__((address_space(3))) void*)l, 16, 0, 0);
}

// B=128, T=2048, J=128, D=512  (fp32 inputs per reference)
#define BB 128
#define TT 2048
#define JJ 128
#define DD 512

// ---------------------------------------------------------------------------
// Kernel 1: U fp32 [B][J=128][D=512] -> Ut bf16 [B][D=512][J=128]
// ---------------------------------------------------------------------------
__global__ __launch_bounds__(256) void u_transpose(const float* __restrict__ U,
                                                   u16* __restrict__ Ut) {
  __shared__ u16 tile[128 * 72];
  const int t  = threadIdx.x;
  const int b  = blockIdx.x >> 3;
  const int d0 = (blockIdx.x & 7) << 6;
  const float* src = U + (size_t)b * (JJ * DD);
  u16* dst         = Ut + (size_t)b * (DD * JJ);
#pragma unroll
  for (int i = 0; i < 8; ++i) {            // 128 rows * 16 float4 = 2048 chunks
    int idx = i * 256 + t;
    int j = idx >> 4, c = idx & 15;        // c: float4 chunk in 64-wide slab
    float4v v = *(const float4v*)(src + (size_t)j * DD + d0 + c * 4);
    short4v p;
#pragma unroll
    for (int e = 0; e < 4; ++e) p[e] = (short)f2bf(v[e]);
    *(short4v*)(tile + j * 72 + c * 4) = p; // row stride 144B; 8B aligned
  }
  __syncthreads();
#pragma unroll
  for (int i = 0; i < 4; ++i) {            // 64 d-rows * 16 j-chunks = 1024
    int idx = i * 256 + t;
    int n = idx >> 4, cj = idx & 15;
    short8 vv;
#pragma unroll
    for (int k = 0; k < 8; ++k) vv[k] = (short)tile[(cj * 8 + k) * 72 + n];
    *(short8*)(dst + (size_t)(d0 + n) * JJ + cj * 8) = vv;
  }
}

// ---------------------------------------------------------------------------
// Kernel 2: fused softmax (fp32) + bf16 MFMA GEMM, fp32 out.
// Block = (b, tm): 128 t-rows x FULL 512 d-cols (tn-loop inside; S read 1x).
// r1 structure (staged b_lds, reg-prefetch pipeline, direct acc stores) with
// ONE change: tn-boundary barriers use raw s_barrier + COUNTED s_waitcnt
// vmcnt(16) instead of __syncthreads' vmcnt(0) drain -> output stores stay
// in flight across barriers (T4), store drain overlaps next tile's MFMA.
// ---------------------------------------------------------------------------
__global__ __launch_bounds__(256, 2) void softmax_gemm(const float* __restrict__ S,
                                                       const u16* __restrict__ Ut,
                                                       float* __restrict__ O) {
  __shared__ __align__(16) u16 a_lds[128 * 128];   // 32 KiB
  __shared__ __align__(16) u16 b_lds[128 * 128];   // 32 KiB

  const int tid = threadIdx.x;
  // bijective XCD swizzle (2048 blocks % 8 == 0): same-b blocks share one L2
  const int bid = blockIdx.x;
  const int swz = (bid & 7) * 256 + (bid >> 3);
  const int b   = swz >> 4;
  const int tm  = swz & 15;
  const int wave = tid >> 6, lane = tid & 63;
  const int ml = lane & 15, quad = lane >> 4;
  const int wm = wave & 1, wn = wave >> 1;

  const u16* utb = Ut + (size_t)b * (DD * JJ);     // [512][128] bf16

  // ---- stage B tile tn=0: async global->LDS, source chunk pre-swizzled ----
  // layout [s][n][chunk]: phys chunk qp holds logical chunk qp ^ ((n>>1)&3)
#pragma unroll
  for (int i = 0; i < 8; ++i) {
    int ch = i * 256 + tid;
    int s = ch >> 9, n = (ch >> 2) & 127, qp = ch & 3;
    int c4 = qp ^ ((n >> 1) & 3);
    const u16* g = utb + n * JJ + s * 32 + c4 * 8;
    u16* l = b_lds + (size_t)(i * 256 + wave * 64) * 8;  // wave-uniform base
    llds16(g, l);
  }

  // ---- prefetch B tile 1 into regs (consumed at tn=0's ds_write phase) ----
  int4v pf[8];
#pragma unroll
  for (int i = 0; i < 8; ++i) {
    int ch = i * 256 + tid;
    int s = ch >> 9, n = (ch >> 2) & 127, qp = ch & 3;
    int c4 = qp ^ ((n >> 1) & 3);
    pf[i] = *(const int4v*)(utb + (size_t)128 * JJ + n * JJ + s * 32 + c4 * 8);
  }

  // ---- softmax: 2 threads per row, 64 fp32 each ----
  const int m = tid >> 1, h = tid & 1;
  const float* srow = S + ((size_t)b * TT + tm * 128 + m) * JJ + h * 64;
  float x[64];
#pragma unroll
  for (int c = 0; c < 16; ++c) {
    float4v v = ((const float4v*)srow)[c];
#pragma unroll
    for (int e = 0; e < 4; ++e) x[c * 4 + e] = v[e];
  }
  float mx = -1e30f;
#pragma unroll
  for (int e = 0; e < 64; ++e) mx = fmaxf(mx, x[e]);
  mx = fmaxf(mx, __shfl_xor(mx, 1, 64));
  float sum = 0.f;
#pragma unroll
  for (int e = 0; e < 64; ++e) { x[e] = __expf(x[e] - mx); sum += x[e]; }
  sum += __shfl_xor(sum, 1, 64);
  const float rs = 1.0f / sum;
  // write normalized bf16 into swizzled slab layout:
  // elem (m,k): s=k>>5, q=(k>>3)&3, phys chunk = q ^ ((m>>1)&3)
#pragma unroll
  for (int c = 0; c < 8; ++c) {
    short8 us;
#pragma unroll
    for (int e = 0; e < 8; ++e) us[e] = (short)f2bf(x[c * 8 + e] * rs);
    int s  = h * 2 + (c >> 2);
    int qp = (c & 3) ^ ((m >> 1) & 3);
    *(short8*)(a_lds + s * 4096 + m * 32 + qp * 8) = us;
  }

  // full drain here is fine: no output stores outstanding yet; drains the
  // b-tile global_load_lds + pf loads + a_lds ds_writes in one go.
  __syncthreads();

  float* ob = O + ((size_t)b * TT + tm * 128) * DD;

#pragma unroll
  for (int tn = 0; tn < 4; ++tn) {
    // ---- MFMA: D[d][t]; A-operand = Ut frag (bv), B-operand = P frag (av) ----
    float4v acc[4][4];
#pragma unroll
    for (int mi = 0; mi < 4; ++mi)
#pragma unroll
      for (int ni = 0; ni < 4; ++ni) {
        float4v z = {0.f, 0.f, 0.f, 0.f};
        acc[mi][ni] = z;
      }

#pragma unroll
    for (int s = 0; s < 4; ++s) {
      short8 bv[4];
#pragma unroll
      for (int ni = 0; ni < 4; ++ni) {
        int nn = wn * 64 + ni * 16 + ml;
        int qp = quad ^ ((nn >> 1) & 3);
        bv[ni] = *(const short8*)(b_lds + s * 4096 + nn * 32 + qp * 8);
      }
      short8 av[4];
#pragma unroll
      for (int mi = 0; mi < 4; ++mi) {
        int mm = wm * 64 + mi * 16 + ml;
        int qp = quad ^ ((mm >> 1) & 3);
        av[mi] = *(const short8*)(a_lds + s * 4096 + mm * 32 + qp * 8);
      }
#pragma unroll
      for (int mi = 0; mi < 4; ++mi)
#pragma unroll
        for (int ni = 0; ni < 4; ++ni)
          acc[mi][ni] = __builtin_amdgcn_mfma_f32_16x16x32_bf16(
              bv[ni], av[mi], acc[mi][ni], 0, 0, 0);
    }

    // ---- direct float4 stores from acc (issued BEFORE the boundary; they
    //      stay in flight across the counted-vmcnt barriers below) ----
    // acc[mi][ni][r]: t = tm*128 + wm*64 + mi*16 + ml,
    //                 d = tn*128 + wn*64 + ni*16 + quad*4 + r
#pragma unroll
    for (int mi = 0; mi < 4; ++mi) {
      const int t = wm * 64 + mi * 16 + ml;
#pragma unroll
      for (int ni = 0; ni < 4; ++ni) {
        const int d = tn * 128 + wn * 64 + ni * 16 + quad * 4;
        *(float4v*)(ob + (size_t)t * DD + d) = acc[mi][ni];
      }
    }

    if (tn < 3) {
      // ---- T4 boundary: never drain vmcnt to 0 in the loop ----
      // (1) all waves done READING b_lds(tn): own ds ops done + barrier
      asm volatile("s_waitcnt lgkmcnt(0)" ::: "memory");
      __builtin_amdgcn_s_barrier();
      __builtin_amdgcn_sched_barrier(0);
      // (2) pf loads (issued before this tn's 16 stores) retired: queue is
      //     [old stores..., pf(8), stores(16)] -> vmcnt(16) retires through
      //     pf while leaving the current store burst in flight.
      asm volatile("s_waitcnt vmcnt(16)" ::: "memory");
      __builtin_amdgcn_sched_barrier(0);
      // (3) write next B tile (prefetched regs) -> linear LDS (pre-swizzled)
#pragma unroll
      for (int i = 0; i < 8; ++i) {
        int ch = i * 256 + tid;
        *(int4v*)(b_lds + (size_t)ch * 8) = pf[i];
      }
      // (4) issue prefetch for tile tn+2 (after the vmcnt, so it doesn't
      //     extend the wait)
      if (tn < 2) {
        const u16* utn = utb + (size_t)(tn + 2) * 128 * JJ;
#pragma unroll
        for (int i = 0; i < 8; ++i) {
          int ch = i * 256 + tid;
          int s = ch >> 9, n = (ch >> 2) & 127, qp = ch & 3;
          int c4 = qp ^ ((n >> 1) & 3);
          pf[i] = *(const int4v*)(utn + n * JJ + s * 32 + c4 * 8);
        }
      }
      // (5) ds_writes visible to all waves
      asm volatile("s_waitcnt lgkmcnt(0)" ::: "memory");
      __builtin_amdgcn_s_barrier();
      __builtin_amdgcn_sched_barrier(0);
    }
  }
}

// ---------------------------------------------------------------------------
extern "C" void kernel_launch(void* const* d_in, const int* in_sizes, int n_in,
                              void* d_out, int out_size, void* d_ws, size_t ws_size,
                              hipStream_t stream) {
  (void)in_sizes; (void)n_in; (void)out_size; (void)ws_size;
  const float* U = (const float*)d_in[0];  // [128][128][512] fp32
  const float* S = (const float*)d_in[1];  // [128][2048][128] fp32
  float* out = (float*)d_out;              // [128][2048][512] fp32
  u16* Ut    = (u16*)d_ws;                 // [128][512][128] bf16 = 8 MiB scratch

  u_transpose<<<BB * 8, 256, 0, stream>>>(U, Ut);
  softmax_gemm<<<BB * 16, 256, 0, stream>>>(S, Ut, out);
}